// Round 1
// baseline (6339.465 us; speedup 1.0000x reference)
//
#include <hip/hip_runtime.h>
#include <hip/hip_bf16.h>

// Problem constants
#define BB 2
#define HH 96
#define WW 96
#define HW (HH*WW)
#define CIN 128
#define GG 8
#define CG 16
#define KK 9
#define OMC 216   // G*3*K = 216
#define PPX 4     // pixels per block in deform kernel

// ---------------------------------------------------------------------------
// diff = a - b, vectorized float4
__global__ void sub_kernel(const float4* __restrict__ a, const float4* __restrict__ b,
                           float4* __restrict__ o, int n4) {
    int i = blockIdx.x * blockDim.x + threadIdx.x;
    if (i < n4) {
        float4 x = a[i], y = b[i];
        o[i] = make_float4(x.x - y.x, x.y - y.y, x.z - y.z, x.w - y.w);
    }
}

// ---------------------------------------------------------------------------
// Direct 3x3 conv, pad=1, optional second input (channel-concat), optional relu.
// Thread = one output element (b, o, h, w). Layout NCHW.
__global__ __launch_bounds__(256) void conv3x3_dual(
    const float* __restrict__ in1, int Cin1,
    const float* __restrict__ in2, int Cin2,
    const float* __restrict__ wgt,   // (Cout, Cin1+Cin2, 3, 3)
    const float* __restrict__ bias,  // (Cout)
    float* __restrict__ out,         // (B, Cout, H, W)
    int Cout, int do_relu)
{
    int idx = blockIdx.x * 256 + threadIdx.x;
    int total = BB * Cout * HW;
    if (idx >= total) return;

    int x  = idx % WW;
    int y  = (idx / WW) % HH;
    int o  = (idx / HW) % Cout;
    int b  = idx / (HW * Cout);

    int Cin = Cin1 + Cin2;
    float acc = bias[o];
    const float* wrow = wgt + (size_t)o * Cin * 9;

    for (int ci = 0; ci < Cin; ++ci) {
        const float* src;
        int cc, cbase;
        if (ci < Cin1) { src = in1; cc = ci;        cbase = b * Cin1; }
        else           { src = in2; cc = ci - Cin1; cbase = b * Cin2; }
        const float* ip = src + (size_t)(cbase + cc) * HW;
        const float* wc = wrow + ci * 9;

        #pragma unroll
        for (int ky = 0; ky < 3; ++ky) {
            int yy = y + ky - 1;
            if (yy < 0 || yy >= HH) continue;
            const float* r = ip + yy * WW;
            float wA = wc[ky*3 + 0], wB = wc[ky*3 + 1], wC = wc[ky*3 + 2];
            if (x > 0)      acc += r[x-1] * wA;
                            acc += r[x  ] * wB;
            if (x < WW-1)   acc += r[x+1] * wC;
        }
    }
    if (do_relu) acc = fmaxf(acc, 0.f);
    out[idx] = acc;
}

// ---------------------------------------------------------------------------
// Deformable conv v2: x=(B,128,H,W), om=(B,216,H,W) where channels 0..143 are
// offsets (per group g: ch g*18+2k = dy, g*18+2k+1 = dx) and 144..215 are raw
// mask logits (ch 144 + g*9 + k). Output = relu(dcn + bias), (B,128,H,W).
__global__ __launch_bounds__(128) void deform_kernel(
    const float* __restrict__ x,
    const float* __restrict__ om,
    const float* __restrict__ wgt,   // (128, 128, 3, 3)
    const float* __restrict__ bias,  // (128)
    float* __restrict__ out)
{
    __shared__ float s_cw[PPX][72][4];           // corner weight * mask
    __shared__ int   s_ci[PPX][72][4];           // clamped spatial index y*W+x
    __shared__ __align__(16) float s_v[PPX][1152]; // sampled values, [ci*9+k]

    int tid  = threadIdx.x;
    int pix0 = blockIdx.x * PPX;

    // Phase A: per (pixel, g, k) compute bilinear corners
    for (int e = tid; e < PPX * 72; e += 128) {
        int p   = e / 72, gk = e % 72;
        int pix = pix0 + p;
        int b   = pix / HW, rem = pix % HW;
        int h   = rem / WW, w = rem % WW;
        int g   = gk / 9, k = gk % 9;

        int obase = b * OMC * HW + rem;
        float dy = om[obase + (g*18 + 2*k    ) * HW];
        float dx = om[obase + (g*18 + 2*k + 1) * HW];
        float mr = om[obase + (144 + g*9 + k ) * HW];
        float m  = 1.f / (1.f + expf(-mr));

        float py = dy + (float)(k / 3) + (float)h - 1.f;
        float px = dx + (float)(k % 3) + (float)w - 1.f;
        float fy = floorf(py), fx = floorf(px);
        int   y0 = (int)fy,    x0 = (int)fx;
        float ly = py - fy,    lx = px - fx;

        float cw[4] = { (1.f-ly)*(1.f-lx), (1.f-ly)*lx, ly*(1.f-lx), ly*lx };
        #pragma unroll
        for (int j = 0; j < 4; ++j) {
            int yy = y0 + (j >> 1);
            int xx = x0 + (j & 1);
            bool valid = (yy >= 0) && (yy < HH) && (xx >= 0) && (xx < WW);
            int yc = min(max(yy, 0), HH-1);
            int xc = min(max(xx, 0), WW-1);
            s_ci[p][gk][j] = yc * WW + xc;
            s_cw[p][gk][j] = valid ? cw[j] * m : 0.f;
        }
    }
    __syncthreads();

    // Phase B: gather 1152 samples per pixel into LDS
    for (int e = tid; e < PPX * 1152; e += 128) {
        int p   = e / 1152, i = e % 1152;
        int pix = pix0 + p;
        int b   = pix / HW;
        int ci  = i / 9, k = i % 9;
        int g   = ci >> 4;
        int gk  = g * 9 + k;
        const float* plane = x + (size_t)(b * CIN + ci) * HW;
        float v = s_cw[p][gk][0] * plane[s_ci[p][gk][0]]
                + s_cw[p][gk][1] * plane[s_ci[p][gk][1]]
                + s_cw[p][gk][2] * plane[s_ci[p][gk][2]]
                + s_cw[p][gk][3] * plane[s_ci[p][gk][3]];
        s_v[p][i] = v;
    }
    __syncthreads();

    // Phase C: 128 output channels, one per thread; dot over 1152 samples
    int o = tid;
    float acc0 = bias[o], acc1 = acc0, acc2 = acc0, acc3 = acc0;
    const float4* wv = (const float4*)(wgt + (size_t)o * 1152);
    const float4* v0 = (const float4*)&s_v[0][0];
    const float4* v1 = (const float4*)&s_v[1][0];
    const float4* v2 = (const float4*)&s_v[2][0];
    const float4* v3 = (const float4*)&s_v[3][0];
    #pragma unroll 4
    for (int i = 0; i < 288; ++i) {
        float4 wq = wv[i];
        float4 a0 = v0[i]; acc0 += wq.x*a0.x + wq.y*a0.y + wq.z*a0.z + wq.w*a0.w;
        float4 a1 = v1[i]; acc1 += wq.x*a1.x + wq.y*a1.y + wq.z*a1.z + wq.w*a1.w;
        float4 a2 = v2[i]; acc2 += wq.x*a2.x + wq.y*a2.y + wq.z*a2.z + wq.w*a2.w;
        float4 a3 = v3[i]; acc3 += wq.x*a3.x + wq.y*a3.y + wq.z*a3.z + wq.w*a3.w;
    }
    float accs[4] = {acc0, acc1, acc2, acc3};
    #pragma unroll
    for (int p = 0; p < PPX; ++p) {
        int pix = pix0 + p;
        int b   = pix / HW, rem = pix % HW;
        out[(size_t)(b * 128 + o) * HW + rem] = fmaxf(accs[p], 0.f);
    }
}

// ---------------------------------------------------------------------------
extern "C" void kernel_launch(void* const* d_in, const int* in_sizes, int n_in,
                              void* d_out, int out_size, void* d_ws, size_t ws_size,
                              hipStream_t stream) {
    const float* R1    = (const float*)d_in[0];
    const float* Q0    = (const float*)d_in[1];
    const float* w1    = (const float*)d_in[2];
    const float* b1    = (const float*)d_in[3];
    const float* w2    = (const float*)d_in[4];
    const float* b2    = (const float*)d_in[5];
    const float* w_om  = (const float*)d_in[6];
    const float* b_om  = (const float*)d_in[7];
    const float* w_dcn = (const float*)d_in[8];
    const float* b_dcn = (const float*)d_in[9];
    const float* w_rq  = (const float*)d_in[10];
    const float* b_rq  = (const float*)d_in[11];
    float* outp = (float*)d_out;

    const int NACT = BB * CIN * HW;      // 2359296
    float* buf0 = (float*)d_ws;          // diff, then t2
    float* buf1 = buf0 + NACT;           // t1, then fea
    float* buf2 = buf1 + NACT;           // om (BB*216*HW = 3981312)

    // 1. diff = R1 - Q0
    sub_kernel<<<(NACT/4 + 255)/256, 256, 0, stream>>>(
        (const float4*)R1, (const float4*)Q0, (float4*)buf0, NACT/4);

    // 2. off = relu(conv(diff, w1, b1))
    conv3x3_dual<<<(BB*128*HW)/256, 256, 0, stream>>>(
        buf0, 128, nullptr, 0, w1, b1, buf1, 128, 1);

    // 3. off = relu(conv(off, w2, b2))
    conv3x3_dual<<<(BB*128*HW)/256, 256, 0, stream>>>(
        buf1, 128, nullptr, 0, w2, b2, buf0, 128, 1);

    // 4. om = conv(off, w_om, b_om)   (no relu)
    conv3x3_dual<<<(BB*OMC*HW)/256, 256, 0, stream>>>(
        buf0, 128, nullptr, 0, w_om, b_om, buf2, OMC, 0);

    // 5. fea = relu(deform_conv(R1, om, w_dcn, b_dcn))
    deform_kernel<<<(BB*HW)/PPX, 128, 0, stream>>>(
        R1, buf2, w_dcn, b_dcn, buf1);

    // 6. out = relu(conv(concat(fea, Q0), w_rq, b_rq))
    conv3x3_dual<<<(BB*128*HW)/256, 256, 0, stream>>>(
        buf1, 128, Q0, 128, w_rq, b_rq, outp, 128, 1);
}

// Round 4
// 697.653 us; speedup vs baseline: 9.0869x; 9.0869x over previous
//
#include <hip/hip_runtime.h>

#define HH 96
#define WW 96
#define HW 9216
#define NPIX 18432      // B*H*W, B=2
#define OMC 216

typedef __attribute__((ext_vector_type(8))) short short8x;       // MFMA bf16 frag
typedef __attribute__((ext_vector_type(8))) unsigned short ushort8x;
typedef __attribute__((ext_vector_type(4))) float f32x4;

__device__ __forceinline__ f32x4 mfma16(short8x a, short8x b, f32x4 c) {
    return __builtin_amdgcn_mfma_f32_16x16x32_bf16(a, b, c, 0, 0, 0);
}
__device__ __forceinline__ unsigned short f2bf(float f) {
    unsigned int u = __float_as_uint(f);
    u = (u + 0x7FFFu + ((u >> 16) & 1u)) >> 16;   // RNE (finite values)
    return (unsigned short)u;
}
__device__ __forceinline__ float bf2f(unsigned short b) {
    return __uint_as_float((unsigned int)b << 16);
}
__device__ __forceinline__ void split2(float v, unsigned short& h, unsigned short& l) {
    h = f2bf(v);
    l = f2bf(v - bf2f(h));
}

// ---------------------------------------------------------------------------
// NCHW fp32 -> r1f (fp32 NHWC, gather src), diff=R1-Q0 (hi/lo bf16, conv1 in),
// Q0 -> cat channels (hi at 128..255, lo at 384..511). 64 pixels per block.
__global__ __launch_bounds__(256) void prep_acts(
    const float* __restrict__ R1, const float* __restrict__ Q0,
    float* __restrict__ r1f,             // [NPIX][128] fp32
    unsigned short* __restrict__ diffb,  // [NPIX][256] hi|lo
    unsigned short* __restrict__ cat)    // [NPIX][512]
{
    __shared__ float tR[128][64];
    __shared__ float tQ[128][64];
    int tid = threadIdx.x;
    int p0  = blockIdx.x * 64;
    int b   = p0 / HW;
    int rem0 = p0 % HW;

    for (int e = tid; e < 2048; e += 256) {          // 128 ch x 16 float4
        int c = e >> 4, j = e & 15;
        size_t base = ((size_t)(b * 128 + c)) * HW + rem0;
        *(float4*)&tR[c][j * 4] = *(const float4*)(R1 + base + j * 4);
        *(float4*)&tQ[c][j * 4] = *(const float4*)(Q0 + base + j * 4);
    }
    __syncthreads();

    int p = tid & 63, half = tid >> 6;   // half 0..3
    int c0 = half * 32;
    size_t px = (size_t)p0 + p;
    float rv[32];
    ushort8x dh[4], dl[4], qh[4], ql[4];
    #pragma unroll
    for (int cc = 0; cc < 32; ++cc) {
        float r = tR[c0 + cc][p], q = tQ[c0 + cc][p];
        rv[cc] = r;
        unsigned short h, l;
        split2(r - q, h, l); dh[cc >> 3][cc & 7] = h; dl[cc >> 3][cc & 7] = l;
        split2(q, h, l);     qh[cc >> 3][cc & 7] = h; ql[cc >> 3][cc & 7] = l;
    }
    #pragma unroll
    for (int i = 0; i < 8; ++i)
        *(float4*)&r1f[px * 128 + c0 + i * 4] = *(float4*)&rv[i * 4];
    #pragma unroll
    for (int i = 0; i < 4; ++i) {
        *(ushort8x*)&diffb[px * 256 +       c0 + i * 8] = dh[i];
        *(ushort8x*)&diffb[px * 256 + 128 + c0 + i * 8] = dl[i];
        *(ushort8x*)&cat [px * 512 + 128 + c0 + i * 8] = qh[i];
        *(ushort8x*)&cat [px * 512 + 384 + c0 + i * 8] = ql[i];
    }
}

// ---------------------------------------------------------------------------
// Weight repack to bf16 hi/lo planes.
// p1/p2: [2][9][128][128]  (tap-major, [t][o][ci])
// pom:   [2][9][256][128]  (o padded to 256)
// prq:   [2][9][128][256]
// pdcn:  [2][128][1152]    K-order = k*128+ci (tap-major within row)
__global__ __launch_bounds__(256) void prep_w(
    const float* __restrict__ w1, const float* __restrict__ w2,
    const float* __restrict__ wom, const float* __restrict__ bom,
    const float* __restrict__ wrq, const float* __restrict__ wdcn,
    unsigned short* __restrict__ p1, unsigned short* __restrict__ p2,
    unsigned short* __restrict__ pom, unsigned short* __restrict__ prq,
    unsigned short* __restrict__ pdcn, float* __restrict__ bomp)
{
    int idx = blockIdx.x * 256 + threadIdx.x;
    unsigned short h, l;
    if (idx < 147456) {                   // 9*128*128
        int t = idx / 16384, o = (idx >> 7) & 127, ci = idx & 127;
        int src = (o * 128 + ci) * 9 + t;
        split2(w1[src], h, l);  p1[idx] = h;  p1[idx + 147456] = l;
        split2(w2[src], h, l);  p2[idx] = h;  p2[idx + 147456] = l;
        int dd = o * 1152 + t * 128 + ci;
        split2(wdcn[src], h, l); pdcn[dd] = h; pdcn[dd + 147456] = l;
    }
    if (idx < 294912) {
        { // om
            int t = idx / 32768, o = (idx >> 7) & 255, ci = idx & 127;
            float v = (o < OMC) ? wom[(o * 128 + ci) * 9 + t] : 0.f;
            split2(v, h, l); pom[idx] = h; pom[idx + 294912] = l;
        }
        { // rq
            int t = idx / 32768, o = (idx >> 8) & 127, ci = idx & 255;
            split2(wrq[(o * 256 + ci) * 9 + t], h, l);
            prq[idx] = h; prq[idx + 294912] = l;
        }
    }
    if (idx < 256) bomp[idx] = (idx < OMC) ? bom[idx] : 0.f;
}

// ---------------------------------------------------------------------------
// Shift-GEMM 3x3 conv, pad=1, hi/lo bf16 NHWC in (row = [CIN hi][CIN lo]),
// split weights, MFMA 16x16x32, 3-product compensation.
// MODE 0: bf16 hi/lo out, row stride 2*COUTP. MODE 1: single-bf16 [pix][216].
// MODE 2: fp32 NCHW.
template<int CIN, int COUTP, int MODE, bool RELU>
__global__ __launch_bounds__(256, 2) void conv_mfma(
    const unsigned short* __restrict__ in,   // [NPIX][2*CIN]
    const unsigned short* __restrict__ wpk,  // [2][9][COUTP][CIN]
    const float* __restrict__ bias,          // [COUTP]
    void* __restrict__ outv)
{
    const size_t WPLANE = (size_t)9 * COUTP * CIN;
    int tid = threadIdx.x;
    int wid = tid >> 6, lane = tid & 63;
    int r = lane & 15, q = lane >> 4;
    int pblk = blockIdx.x * 32;
    int n0 = blockIdx.y * 128 + wid * 32;
    int b = pblk / HW;
    int prem = pblk % HW;

    f32x4 acc[2][2] = {};

    #pragma unroll
    for (int t = 0; t < 9; ++t) {
        const int dy = t / 3 - 1, dx = t % 3 - 1;
        const unsigned short* wt = wpk + ((size_t)t * COUTP + n0 + r) * CIN + q * 8;
        const unsigned short* ap[2];
        bool av[2];
        #pragma unroll
        for (int g = 0; g < 2; ++g) {
            int pg = prem + g * 16;
            int yg = pg / 96 + dy;
            int xg = pg % 96 + r + dx;
            av[g] = ((unsigned)yg < 96u) && ((unsigned)xg < 96u);
            ap[g] = in + ((size_t)b * HW + yg * 96 + xg) * (2 * CIN) + q * 8;
        }
        #pragma unroll
        for (int kc = 0; kc < CIN / 32; ++kc) {
            short8x a0h = {}, a0l = {}, a1h = {}, a1l = {};
            if (av[0]) {
                a0h = *(const short8x*)(ap[0] + kc * 32);
                a0l = *(const short8x*)(ap[0] + CIN + kc * 32);
            }
            if (av[1]) {
                a1h = *(const short8x*)(ap[1] + kc * 32);
                a1l = *(const short8x*)(ap[1] + CIN + kc * 32);
            }
            short8x w0h = *(const short8x*)(wt + kc * 32);
            short8x w1h = *(const short8x*)(wt + (size_t)16 * CIN + kc * 32);
            short8x w0l = *(const short8x*)(wt + WPLANE + kc * 32);
            short8x w1l = *(const short8x*)(wt + WPLANE + (size_t)16 * CIN + kc * 32);
            acc[0][0] = mfma16(a0h, w0h, acc[0][0]);
            acc[1][0] = mfma16(a1h, w0h, acc[1][0]);
            acc[0][1] = mfma16(a0h, w1h, acc[0][1]);
            acc[1][1] = mfma16(a1h, w1h, acc[1][1]);
            acc[0][0] = mfma16(a0l, w0h, acc[0][0]);
            acc[1][0] = mfma16(a1l, w0h, acc[1][0]);
            acc[0][1] = mfma16(a0l, w1h, acc[0][1]);
            acc[1][1] = mfma16(a1l, w1h, acc[1][1]);
            acc[0][0] = mfma16(a0h, w0l, acc[0][0]);
            acc[1][0] = mfma16(a1h, w0l, acc[1][0]);
            acc[0][1] = mfma16(a0h, w1l, acc[0][1]);
            acc[1][1] = mfma16(a1h, w1l, acc[1][1]);
        }
    }

    #pragma unroll
    for (int g = 0; g < 2; ++g) {
        #pragma unroll
        for (int ni = 0; ni < 2; ++ni) {
            int o = n0 + ni * 16 + r;
            float bv = bias[o];
            #pragma unroll
            for (int j = 0; j < 4; ++j) {
                int pixel = pblk + g * 16 + q * 4 + j;
                float v = acc[g][ni][j] + bv;
                if (RELU) v = fmaxf(v, 0.f);
                if (MODE == 0) {
                    unsigned short h, l; split2(v, h, l);
                    ((unsigned short*)outv)[(size_t)pixel * 2 * COUTP + o] = h;
                    ((unsigned short*)outv)[(size_t)pixel * 2 * COUTP + COUTP + o] = l;
                } else if (MODE == 1) {
                    if (o < OMC) ((unsigned short*)outv)[(size_t)pixel * OMC + o] = f2bf(v);
                } else {
                    int bb = pixel / HW, rm = pixel % HW;
                    ((float*)outv)[((size_t)bb * 128 + o) * HW + rm] = v;
                }
            }
        }
    }
}

// ---------------------------------------------------------------------------
// Deformable conv v2, split precision. 16 pixels/block, 256 threads.
// Phase AB (fused): per (pixel, group, tap) compute bilinear corners from bf16
// offsets, gather 16 fp32 channels, scale by mask*corner weights, split hi/lo
// into XOR-swizzled LDS (K-order = k*128+c, matching pdcn). Phase C: 3-product
// MFMA over K=1152; relu(acc+bias) -> cat channels (hi 0..127, lo 256..383).
__global__ __launch_bounds__(256) void deform_mfma(
    const float* __restrict__ xf,            // [NPIX][128] fp32 NHWC (R1)
    const unsigned short* __restrict__ omf,  // [NPIX][216] bf16
    const unsigned short* __restrict__ wpk,  // [2][128][1152]
    const float* __restrict__ bias,          // [128]
    unsigned short* __restrict__ cat)        // [NPIX][512]
{
    __shared__ __align__(16) unsigned short s_vh[16][1152];
    __shared__ __align__(16) unsigned short s_vl[16][1152];

    int tid = threadIdx.x;
    int pix0 = blockIdx.x * 16;
    int b = pix0 / HW;

    for (int e = tid; e < 1152; e += 256) {
        int p = e / 72, gk = e % 72;
        int pix = pix0 + p;
        int rem = pix % HW;
        int hh = rem / 96, ww = rem % 96;
        int g = gk / 9, k = gk % 9;
        const unsigned short* op = omf + (size_t)pix * OMC;
        float dy = bf2f(op[g * 18 + 2 * k]);
        float dx = bf2f(op[g * 18 + 2 * k + 1]);
        float mr = bf2f(op[144 + g * 9 + k]);
        float m = 1.f / (1.f + __expf(-mr));
        float py = dy + (float)(k / 3) + (float)hh - 1.f;
        float px = dx + (float)(k % 3) + (float)ww - 1.f;
        float fy = floorf(py), fx = floorf(px);
        int y0 = (int)fy, x0 = (int)fx;
        float ly = py - fy, lx = px - fx;
        float cw[4] = {(1.f - ly) * (1.f - lx), (1.f - ly) * lx,
                       ly * (1.f - lx), ly * lx};
        const float* cp[4];
        #pragma unroll
        for (int j = 0; j < 4; ++j) {
            int yy = y0 + (j >> 1), xx = x0 + (j & 1);
            bool valid = (yy >= 0) && (yy < HH) && (xx >= 0) && (xx < WW);
            int yc = yy < 0 ? 0 : (yy > 95 ? 95 : yy);
            int xc = xx < 0 ? 0 : (xx > 95 ? 95 : xx);
            cp[j] = xf + ((size_t)(b * HW + yc * 96 + xc)) * 128 + g * 16;
            cw[j] = valid ? cw[j] * m : 0.f;
        }
        int swz = (p & 7) << 3;
        int i0 = k * 128 + g * 16;
        ushort8x vh[2], vl[2];
        #pragma unroll
        for (int cq = 0; cq < 4; ++cq) {
            float4 v0 = *(const float4*)(cp[0] + cq * 4);
            float4 v1 = *(const float4*)(cp[1] + cq * 4);
            float4 v2 = *(const float4*)(cp[2] + cq * 4);
            float4 v3 = *(const float4*)(cp[3] + cq * 4);
            float vv[4] = {
                cw[0]*v0.x + cw[1]*v1.x + cw[2]*v2.x + cw[3]*v3.x,
                cw[0]*v0.y + cw[1]*v1.y + cw[2]*v2.y + cw[3]*v3.y,
                cw[0]*v0.z + cw[1]*v1.z + cw[2]*v2.z + cw[3]*v3.z,
                cw[0]*v0.w + cw[1]*v1.w + cw[2]*v2.w + cw[3]*v3.w};
            #pragma unroll
            for (int cc = 0; cc < 4; ++cc) {
                unsigned short h, l;
                split2(vv[cc], h, l);
                int ei = cq * 4 + cc;
                vh[ei >> 3][ei & 7] = h;
                vl[ei >> 3][ei & 7] = l;
            }
        }
        *(ushort8x*)&s_vh[p][(i0    ) ^ swz] = vh[0];
        *(ushort8x*)&s_vh[p][(i0 + 8) ^ swz] = vh[1];
        *(ushort8x*)&s_vl[p][(i0    ) ^ swz] = vl[0];
        *(ushort8x*)&s_vl[p][(i0 + 8) ^ swz] = vl[1];
    }
    __syncthreads();

    // Phase C: M=16 pixels x N=128 outs; each wave 32 outs.
    int wid = tid >> 6, lane = tid & 63;
    int r = lane & 15, q = lane >> 4;
    int n0 = wid * 32;
    f32x4 acc0 = {}, acc1 = {};
    const unsigned short* wb = wpk + (size_t)(n0 + r) * 1152 + q * 8;
    int swz = (r & 7) << 3;
    #pragma unroll 4
    for (int kc = 0; kc < 36; ++kc) {
        int e0 = (kc * 32 + q * 8) ^ swz;
        short8x ah = *(const short8x*)&s_vh[r][e0];
        short8x al = *(const short8x*)&s_vl[r][e0];
        short8x b0h = *(const short8x*)(wb + kc * 32);
        short8x b1h = *(const short8x*)(wb + (size_t)16 * 1152 + kc * 32);
        short8x b0l = *(const short8x*)(wb + 147456 + kc * 32);
        short8x b1l = *(const short8x*)(wb + 147456 + (size_t)16 * 1152 + kc * 32);
        acc0 = mfma16(ah, b0h, acc0);
        acc1 = mfma16(ah, b1h, acc1);
        acc0 = mfma16(al, b0h, acc0);
        acc1 = mfma16(al, b1h, acc1);
        acc0 = mfma16(ah, b0l, acc0);
        acc1 = mfma16(ah, b1l, acc1);
    }
    #pragma unroll
    for (int ni = 0; ni < 2; ++ni) {
        f32x4 A = ni ? acc1 : acc0;
        int o = n0 + ni * 16 + r;
        float bv = bias[o];
        #pragma unroll
        for (int j = 0; j < 4; ++j) {
            int pixel = pix0 + q * 4 + j;
            float v = fmaxf(A[j] + bv, 0.f);
            unsigned short h, l;
            split2(v, h, l);
            cat[(size_t)pixel * 512 + o] = h;
            cat[(size_t)pixel * 512 + 256 + o] = l;
        }
    }
}

// ---------------------------------------------------------------------------
extern "C" void kernel_launch(void* const* d_in, const int* in_sizes, int n_in,
                              void* d_out, int out_size, void* d_ws, size_t ws_size,
                              hipStream_t stream) {
    const float* R1    = (const float*)d_in[0];
    const float* Q0    = (const float*)d_in[1];
    const float* w1    = (const float*)d_in[2];
    const float* b1    = (const float*)d_in[3];
    const float* w2    = (const float*)d_in[4];
    const float* b2    = (const float*)d_in[5];
    const float* w_om  = (const float*)d_in[6];
    const float* b_om  = (const float*)d_in[7];
    const float* w_dcn = (const float*)d_in[8];
    const float* b_dcn = (const float*)d_in[9];
    const float* w_rq  = (const float*)d_in[10];
    const float* b_rq  = (const float*)d_in[11];
    float* outp = (float*)d_out;

    // Arena: 51,315,712 bytes total (~48.9 MiB) — omf aliases t1 (dead after conv2).
    char* w = (char*)d_ws;
    float*          r1f   = (float*)w;          w += (size_t)NPIX * 128 * 4;  // 9.44 MB
    unsigned short* diffb = (unsigned short*)w; w += (size_t)NPIX * 256 * 2;  // 9.44 MB (also t2)
    unsigned short* t1    = (unsigned short*)w; w += (size_t)NPIX * 256 * 2;  // 9.44 MB (also omf)
    unsigned short* catb  = (unsigned short*)w; w += (size_t)NPIX * 512 * 2;  // 18.87 MB
    unsigned short* p1    = (unsigned short*)w; w += 2 * 147456 * 2;
    unsigned short* p2    = (unsigned short*)w; w += 2 * 147456 * 2;
    unsigned short* pdcn  = (unsigned short*)w; w += 2 * 147456 * 2;
    unsigned short* pom   = (unsigned short*)w; w += 2 * 294912 * 2;
    unsigned short* prq   = (unsigned short*)w; w += 2 * 294912 * 2;
    float*          bomp  = (float*)w;          w += 256 * 4;
    unsigned short* t2    = diffb;   // diff dead after conv1
    unsigned short* omf   = t1;      // t1 dead after conv2; bf16 [NPIX][216]

    prep_acts<<<288, 256, 0, stream>>>(R1, Q0, r1f, diffb, catb);
    prep_w<<<1152, 256, 0, stream>>>(w1, w2, w_om, b_om, w_rq, w_dcn,
                                     p1, p2, pom, prq, pdcn, bomp);

    conv_mfma<128, 128, 0, true ><<<dim3(576, 1), 256, 0, stream>>>(diffb, p1, b1, t1);
    conv_mfma<128, 128, 0, true ><<<dim3(576, 1), 256, 0, stream>>>(t1,    p2, b2, t2);
    conv_mfma<128, 256, 1, false><<<dim3(576, 2), 256, 0, stream>>>(t2,   pom, bomp, omf);

    deform_mfma<<<1152, 256, 0, stream>>>(r1f, omf, pdcn, b_dcn, catb);

    conv_mfma<256, 128, 2, true ><<<dim3(576, 1), 256, 0, stream>>>(catb, prq, b_rq, outp);
}